// Round 16
// baseline (263.180 us; speedup 1.0000x reference)
//
#include <hip/hip_runtime.h>
#include <stdint.h>

#define D   512      // embedding dim; also bytes per row in fp8
#define BM  128      // A strip rows per block (64 KB LDS)
#define BN  256      // B cols per swept tile (8 waves: 2x4 grid of 64x64)
#define GRP 8        // consecutive B-tiles swept per block (A persists in LDS)

typedef __attribute__((ext_vector_type(4))) float f32x4;   // MFMA accumulator
typedef __attribute__((ext_vector_type(8))) int  i32x8;    // 32B MX A/B fragment

union frag32 { i32x8 v; uint4 q[2]; };

__device__ __forceinline__ void gld_lds16(const void* g, void* l) {
  __builtin_amdgcn_global_load_lds(
      (const __attribute__((address_space(1))) void*)g,
      (__attribute__((address_space(3))) void*)l, 16, 0, 0);
}

__device__ __forceinline__ float fast_exp2(float x) {
#if __has_builtin(__builtin_amdgcn_exp2f)
  return __builtin_amdgcn_exp2f(x);      // raw v_exp_f32
#else
  return exp2f(x);
#endif
}

// 16 rows per 1024-thread block (one wave per row): load 512 fp32, shuffle-reduce
// sumsq, write 512 fp8 (e4m3, x16 pre-scale; undone by scale/256 in the GEMM).
// r21 norm (kept byte-identical): unit-stride loads; outputs byte-identical.
// A (img): row-major, two coalesced dword stores per lane.
// B (prof): PRE-PACKED in MFMA B-operand fragment order
//   byte k of row r -> (r>>4)*8192 + (k>>7)*2048 + ((k>>5)&3)*512 + (r&15)*32 + (k&31)
//   staged through LDS so the global write is one fully-coalesced 8 KB block store.
__global__ __launch_bounds__(1024) void norm_kernel(
    const float* __restrict__ img, const float* __restrict__ prof,
    uint8_t* __restrict__ outA, uint8_t* __restrict__ outB,
    float* __restrict__ out, int n) {
  __shared__ __align__(16) uint8_t st[16 * 512];   // 8 KB packed staging
  if (blockIdx.x == 0 && threadIdx.x == 0) out[0] = 0.0f;

  int wave = threadIdx.x >> 6, lane = threadIdx.x & 63;
  int base = blockIdx.x * 16;            // 16 consecutive rows per block
  if (base >= 2 * n) return;
  bool isA = base < n;
  int row = (isA ? base : base - n) + wave;
  const float* src = (isA ? img : prof) + (size_t)row * D;

  const float4* s4 = (const float4*)src;
  float4 a = s4[lane], b = s4[64 + lane];          // unit-stride per instr
  float ss = a.x*a.x + a.y*a.y + a.z*a.z + a.w*a.w
           + b.x*b.x + b.y*b.y + b.z*b.z + b.w*b.w;
#pragma unroll
  for (int m = 1; m < 64; m <<= 1) ss += __shfl_xor(ss, m, 64);
  float inv = 16.0f / fmaxf(sqrtf(ss), 1e-12f);

  // Pairs are (elem 2j, 2j+1) -> byte values identical to original packing.
  uint32_t lo = __builtin_amdgcn_cvt_pk_fp8_f32(a.x*inv, a.y*inv, 0,  false);
  lo          = __builtin_amdgcn_cvt_pk_fp8_f32(a.z*inv, a.w*inv, lo, true);
  uint32_t hi = __builtin_amdgcn_cvt_pk_fp8_f32(b.x*inv, b.y*inv, 0,  false);
  hi          = __builtin_amdgcn_cvt_pk_fp8_f32(b.z*inv, b.w*inv, hi, true);

  if (isA) {
    uint32_t* dst = (uint32_t*)(outA + (size_t)row * D);
    dst[lane]       = lo;                // bytes [4*lane, 4*lane+4)
    dst[256 + lane] = hi;                // bytes [1024+4*lane, +4)
  } else {
    // k1 = 4*lane, k2 = 256+4*lane in the packed-fragment byte order.
    int o1 = ((lane >> 5) << 11) + (((lane >> 3) & 3) << 9)
           + (wave << 5) + ((lane & 7) << 2);
    *(uint32_t*)&st[o1]        = lo;
    *(uint32_t*)&st[o1 + 4096] = hi;
    __syncthreads();
    uint8_t* g = outB + (size_t)(base - n) * 512;  // group base ((row>>4)*8192)
    *(uint2*)(g + threadIdx.x * 8) = *(const uint2*)&st[threadIdx.x * 8];
  }
}

// Exact softplus for the generic (buckets != 1) path.
__device__ __forceinline__ float softplus_f(float x) {
  float ax = fabsf(x);
  float t = __expf(-ax);
  float corr;
  if (__builtin_expect(ax < 5.0f, 0)) corr = __logf(1.0f + t);
  else                                corr = t - 0.5f * t * t;
  return fmaxf(x, 0.0f) + corr;
}

// C = A(img) x B(prof)^T in fp8 e4m3 via MX MFMA 16x16x128, unit scales (e8m0=127).
//
// r27 = r26 + 3-BUFFER RING + COUNTED VMCNT (the T3/T4 port):
//  - r26 MEASURED (the first structural win): gemm 192->172.5, WRITE 32 B
//    (zero-register claim held), VGPR 112, FETCH 36.9 MB (B fetched once),
//    MfmaUtil 34.6. Undershoot vs prediction: __syncthreads drains vmcnt(0)
//    each kc-step -> the stage must land within ITS OWN step; latency spikes
//    serialize into the barrier; 1 block/CU = lockstep waves, no cover.
//  - Fix (m218's strongest-evidence lever, +38-73% counted-vs-drain): 3-chunk
//    ring sB[3][32K]; step c reads buf c%3, stages chunk c+2 into buf
//    (c+2)%3 (freed by the barrier ending step c-1). Barrier = s_waitcnt
//    vmcnt(4) + raw s_barrier: "all but newest 4 loads landed" retires
//    exactly chunk c+1, keeps chunk c+2 in flight (~2 steps of cover). The
//    loop has NO other VMEM ops -> vmcnt counting is exact. Tail: clamped
//    re-stage of the last chunk (identical-write race, benign; keeps
//    vmcnt(4) uniform).
//  - LDS = 64K A + 96K B = 163840 B exactly (160 KiB pool; 512-B alloc
//    granularity: r26's 131584 was 131104 rounded, so no hidden overhead;
//    163840 is already a multiple). Reduction buffer OVERLAYS sA after a
//    full-drain __syncthreads. Registers: zero delta.
//  - Tripwires: launch error -> 160K cap -> revert r26. absmax!=0 -> race.
//    Flat-but-clean -> residual is LDS-pipe/lockstep -> declare.
//
// A LDS swizzle (r5-r10, verified): row r = 32 chunks of 16 B; slot s stores
// global chunk (s&~7)|((s&7)^(r&7)); frag ds_read_b128 = structural-minimum
// 8 addr/bank. B LDS swizzle mirrors it per 16-col group (slot q^(r&7)),
// staged by pre-swizzling the GLOBAL source (both-sides rule, verified r26).
//
// XCD mapping: blockIdx%8 = XCD (m09); each XCD owns a 16-strip bm range.
__global__ __launch_bounds__(512, 1) void siglip_gemm(
    const uint8_t* __restrict__ A, const uint8_t* __restrict__ B,
    const float* __restrict__ scale_p, const float* __restrict__ bias_p,
    const int* __restrict__ buckets_p, float* __restrict__ out, int n) {
  __shared__ __align__(16) uint8_t sA[BM * D];     // 64 KB (overlaid by red)
  __shared__ __align__(16) uint8_t sB[3][32768];   // 96 KB (3-chunk ring)

  int tid = threadIdx.x;
  int lane = tid & 63, wave = tid >> 6;            // 8 waves, 2x4 grid
  int quad = lane >> 4, l16 = lane & 15;

  int nb  = n / BM;                      // 128 strips
  int nbn = n / BN;                      // 64 bn tiles of 256 cols
  int bm, grp;
  if (nb == 128) {                       // n = 16384 fast path
    int xcd  = blockIdx.x & 7;
    int rest = blockIdx.x >> 3;          // 0..127
    bm  = xcd * 16 + (rest & 15);
    grp = rest >> 4;                     // 8 groups of GRP=8 bn-tiles
  } else {
    bm  = blockIdx.x % nb;
    grp = blockIdx.x / nb;
  }
  int gcount = nbn - grp * GRP; if (gcount > GRP) gcount = GRP;
  int C = 4 * gcount;                    // total kc-chunks this block

  int rowB = bm * BM;
  float escale = __expf(scale_p[0]);
  float scale  = escale * (1.0f / 256.0f);      // undo x16 quant pre-scale
  float bias   = bias_p[0];
  const float LOG2E = 1.4426950408889634f;
  float sl2 = scale * LOG2E, bl2 = bias * LOG2E;
  int buckets = buckets_p[0];

  int wm = (wave >> 2) * 64, wn = (wave & 3) * 64;   // 2x4 wave grid
  int colBase = grp * (GRP * BN);

  // Per-thread B-staging offsets (static-indexed, rule #20):
  // linear LDS offset o = i*8192 + tid*16 decodes as (g = o>>11 col-group,
  // r = (o>>7)&15 row, q = (o>>4)&7 slot); source holds slot q^(r&7).
  int so[4], ldo[4];
#pragma unroll
  for (int i = 0; i < 4; i++) {
    int o = i * 8192 + tid * 16;
    int gg = o >> 11, rr = (o >> 7) & 15, qq = (o >> 4) & 7;
    so[i]  = gg * 8192 + rr * 128 + ((qq ^ (rr & 7)) << 4);
    ldo[i] = o;
  }

  // Stage kc-chunk CH (global index; tile CH>>2, kc CH&3) into buf CH%3.
#define STAGE_CH(CH)                                                           \
  {                                                                            \
    int ch_ = (CH);                                                            \
    const uint8_t* Bs = B + (size_t)(colBase + (ch_ >> 2) * BN) * 512          \
                          + (size_t)(ch_ & 3) * 2048;                          \
    uint8_t* dst_ = sB[ch_ % 3];                                               \
    _Pragma("unroll")                                                          \
    for (int i = 0; i < 4; i++)                                                \
      gld_lds16(Bs + so[i], dst_ + ldo[i]);                                    \
  }

  // ---- prologue: stage A strip (xor swizzle) + chunks 0,1; full drain ----
  {
    const uint8_t* Ag = A + (size_t)rowB * D;
#pragma unroll
    for (int p = 0; p < 8; p++) {
      int c = p * 512 + tid;             // 4096 chunks of 16 B
      int r = c >> 5, s = c & 31;
      int j = (s & ~7) | ((s & 7) ^ (r & 7));
      gld_lds16(Ag + (size_t)r * D + j * 16, &sA[c * 16]);
    }
  }
  STAGE_CH(0)
  STAGE_CH(1)
  __syncthreads();                       // full drain once; ring fills after

  f32x4 acc[4][4];
#pragma unroll
  for (int i = 0; i < 4; i++)
#pragma unroll
    for (int j = 0; j < 4; j++) { acc[i][j].x = 0.f; acc[i][j].y = 0.f; acc[i][j].z = 0.f; acc[i][j].w = 0.f; }

  float S1p0 = 0.0f, S1p1 = 0.0f, dsum = 0.0f, local = 0.0f;

  int brow = lane >> 2, bcol = (lane & 3) << 1, be = brow & 7;
  int bgrp0 = (wn >> 4);                 // wave's first 16-col group index
  int colB = colBase;

  for (int g = 0; g < gcount; g++) {
    int cb = 4 * g;

    // ---- 4 kc-steps: stage chunk c+2 (2 steps of flight), compute chunk c,
    //      then vmcnt(4)+s_barrier retires exactly chunk c+1. ----
#pragma unroll
    for (int kc = 0; kc < 4; kc++) {
      int ch  = cb + kc;
      int chn = ch + 2; if (chn >= C) chn = C - 1;   // clamped tail re-stage
      STAGE_CH(chn)

      frag32 af[4];
#pragma unroll
      for (int tm = 0; tm < 4; tm++) {
        int ra = wm + tm * 16 + l16, e = ra & 7;
        const uint8_t* ap = &sA[ra * D + kc * 128];
        af[tm].q[0] = *(const uint4*)(ap + (((2 * quad) ^ e) << 4));
        af[tm].q[1] = *(const uint4*)(ap + (((2 * quad + 1) ^ e) << 4));
      }
      const uint8_t* sBc = sB[ch % 3];
      __builtin_amdgcn_s_setprio(1);
#pragma unroll
      for (int tn = 0; tn < 4; tn++) {
        frag32 bf;                       // B fragment from LDS (swizzled)
        const uint8_t* bp = &sBc[(bgrp0 + tn) * 2048 + brow * 128];
        bf.q[0] = *(const uint4*)(bp + (((bcol)     ^ be) << 4));
        bf.q[1] = *(const uint4*)(bp + (((bcol + 1) ^ be) << 4));
#pragma unroll
        for (int tm = 0; tm < 4; tm++)
          acc[tm][tn] = __builtin_amdgcn_mfma_scale_f32_16x16x128_f8f6f4(
              af[tm].v, bf.v, acc[tm][tn],
              0, 0,            // cbsz/blgp: fp8 e4m3 both
              0, 127,          // scale A: e8m0 127 -> x1.0
              0, 127);         // scale B: e8m0 127 -> x1.0
      }
      __builtin_amdgcn_s_setprio(0);
      // counted barrier: all but the newest 4 loads (chunk c+2) have landed
      asm volatile("s_waitcnt vmcnt(4)" ::: "memory");
      __builtin_amdgcn_s_barrier();
    }

    // ---- register-only epilogue for tile g (chunk flight continues) ----
    if (buckets == 1) {
      // v <= -7.28 always => softplus(v) = e^v (t^2/2 term < 3e-4 total, dropped)
#pragma unroll
      for (int tm = 0; tm < 4; tm++)
#pragma unroll
        for (int tn = 0; tn < 4; tn++)
#pragma unroll
          for (int e = 0; e < 4; e++) {
            float t = fast_exp2(__builtin_fmaf(acc[tm][tn][e], sl2, bl2));
            if (tn & 1) S1p1 += t; else S1p0 += t;
          }
      if (rowB + wm == colB + wn) {      // wave's 64x64 crosses the diagonal
#pragma unroll
        for (int tm = 0; tm < 4; tm++)
#pragma unroll
          for (int e = 0; e < 4; e++)
            if (quad * 4 + e == l16)     // diag: softplus(-v) = softplus(v) - v
              dsum += __builtin_fmaf(acc[tm][tm][e], scale, bias);
      }
    } else {
      unsigned bs = (unsigned)n / (unsigned)buckets;
#pragma unroll
      for (int tm = 0; tm < 4; tm++)
#pragma unroll
        for (int tn = 0; tn < 4; tn++)
#pragma unroll
          for (int e = 0; e < 4; e++) {
            int r = rowB + wm + tm * 16 + quad * 4 + e;
            int c = colB + wn + tn * 16 + l16;
            if ((unsigned)r / bs != (unsigned)c / bs) continue;
            float v = __builtin_fmaf(acc[tm][tn][e], scale, bias);
            local += softplus_f((r == c) ? -v : v);
          }
    }

    // reset accumulators for next tile
#pragma unroll
    for (int i = 0; i < 4; i++)
#pragma unroll
      for (int j = 0; j < 4; j++) { acc[i][j].x = 0.f; acc[i][j].y = 0.f; acc[i][j].z = 0.f; acc[i][j].w = 0.f; }

    colB += BN;
  }
#undef STAGE_CH

  // ---- block reduction: overlay red on sA (all LDS reads done + drain) ----
  float wsum = local + S1p0 + S1p1 - dsum;
#pragma unroll
  for (int m = 1; m < 64; m <<= 1) wsum += __shfl_xor(wsum, m, 64);
  __syncthreads();                       // full drain; sA reads all complete
  float* red = (float*)sA;
  if (lane == 0) red[wave] = wsum;
  __syncthreads();
  if (tid == 0) {
    float bsum = (red[0] + red[1]) + (red[2] + red[3])
               + (red[4] + red[5]) + (red[6] + red[7]);
    atomicAdd(out, bsum * (1.0f / (float)n));
  }
}

extern "C" void kernel_launch(void* const* d_in, const int* in_sizes, int n_in,
                              void* d_out, int out_size, void* d_ws, size_t ws_size,
                              hipStream_t stream) {
  const float* img  = (const float*)d_in[0];
  const float* prof = (const float*)d_in[1];
  const float* lsc  = (const float*)d_in[2];
  const float* bia  = (const float*)d_in[3];
  const int*   bkt  = (const int*)d_in[4];
  float* out = (float*)d_out;

  int n = in_sizes[0] / D;                 // 16384
  uint8_t* wsA = (uint8_t*)d_ws;           // n*512 fp8, row-major
  uint8_t* wsB = wsA + (size_t)n * D;      // n*512 fp8, packed fragment layout

  norm_kernel<<<(2 * n) / 16, 1024, 0, stream>>>(img, prof, wsA, wsB, out, n);
  int nb   = n / BM;                       // 128
  int nbn  = n / BN;                       // 64
  int ngrp = (nbn + GRP - 1) / GRP;        // 8
  siglip_gemm<<<nb * ngrp, 512, 0, stream>>>(wsA, wsB, lsc, bia, bkt, out, n);
}

// Round 17
// 243.291 us; speedup vs baseline: 1.0818x; 1.0818x over previous
//
#include <hip/hip_runtime.h>
#include <stdint.h>

#define D   512      // embedding dim; also bytes per row in fp8
#define BM  128      // A strip rows per block (64 KB LDS)
#define BN  256      // B cols per swept tile (8 waves: 2x4 grid of 64x64)
#define GRP 16       // consecutive B-tiles swept per block (A persists in LDS)

typedef __attribute__((ext_vector_type(4))) float f32x4;   // MFMA accumulator
typedef __attribute__((ext_vector_type(8))) int  i32x8;    // 32B MX A/B fragment

union frag32 { i32x8 v; uint4 q[2]; };

__device__ __forceinline__ void gld_lds16(const void* g, void* l) {
  __builtin_amdgcn_global_load_lds(
      (const __attribute__((address_space(1))) void*)g,
      (__attribute__((address_space(3))) void*)l, 16, 0, 0);
}

__device__ __forceinline__ float fast_exp2(float x) {
#if __has_builtin(__builtin_amdgcn_exp2f)
  return __builtin_amdgcn_exp2f(x);      // raw v_exp_f32
#else
  return exp2f(x);
#endif
}

// 16 rows per 1024-thread block (one wave per row): load 512 fp32, shuffle-reduce
// sumsq, write 512 fp8 (e4m3, x16 pre-scale; undone by scale/256 in the GEMM).
// r21 norm (kept byte-identical): unit-stride loads; outputs byte-identical.
// A (img): row-major, two coalesced dword stores per lane.
// B (prof): PRE-PACKED in MFMA B-operand fragment order
//   byte k of row r -> (r>>4)*8192 + (k>>7)*2048 + ((k>>5)&3)*512 + (r&15)*32 + (k&31)
//   staged through LDS so the global write is one fully-coalesced 8 KB block store.
__global__ __launch_bounds__(1024) void norm_kernel(
    const float* __restrict__ img, const float* __restrict__ prof,
    uint8_t* __restrict__ outA, uint8_t* __restrict__ outB,
    float* __restrict__ out, int n) {
  __shared__ __align__(16) uint8_t st[16 * 512];   // 8 KB packed staging
  if (blockIdx.x == 0 && threadIdx.x == 0) out[0] = 0.0f;

  int wave = threadIdx.x >> 6, lane = threadIdx.x & 63;
  int base = blockIdx.x * 16;            // 16 consecutive rows per block
  if (base >= 2 * n) return;
  bool isA = base < n;
  int row = (isA ? base : base - n) + wave;
  const float* src = (isA ? img : prof) + (size_t)row * D;

  const float4* s4 = (const float4*)src;
  float4 a = s4[lane], b = s4[64 + lane];          // unit-stride per instr
  float ss = a.x*a.x + a.y*a.y + a.z*a.z + a.w*a.w
           + b.x*b.x + b.y*b.y + b.z*b.z + b.w*b.w;
#pragma unroll
  for (int m = 1; m < 64; m <<= 1) ss += __shfl_xor(ss, m, 64);
  float inv = 16.0f / fmaxf(sqrtf(ss), 1e-12f);

  // Pairs are (elem 2j, 2j+1) -> byte values identical to original packing.
  uint32_t lo = __builtin_amdgcn_cvt_pk_fp8_f32(a.x*inv, a.y*inv, 0,  false);
  lo          = __builtin_amdgcn_cvt_pk_fp8_f32(a.z*inv, a.w*inv, lo, true);
  uint32_t hi = __builtin_amdgcn_cvt_pk_fp8_f32(b.x*inv, b.y*inv, 0,  false);
  hi          = __builtin_amdgcn_cvt_pk_fp8_f32(b.z*inv, b.w*inv, hi, true);

  if (isA) {
    uint32_t* dst = (uint32_t*)(outA + (size_t)row * D);
    dst[lane]       = lo;                // bytes [4*lane, 4*lane+4)
    dst[256 + lane] = hi;                // bytes [1024+4*lane, +4)
  } else {
    // k1 = 4*lane, k2 = 256+4*lane in the packed-fragment byte order.
    int o1 = ((lane >> 5) << 11) + (((lane >> 3) & 3) << 9)
           + (wave << 5) + ((lane & 7) << 2);
    *(uint32_t*)&st[o1]        = lo;
    *(uint32_t*)&st[o1 + 4096] = hi;
    __syncthreads();
    uint8_t* g = outB + (size_t)(base - n) * 512;  // group base ((row>>4)*8192)
    *(uint2*)(g + threadIdx.x * 8) = *(const uint2*)&st[threadIdx.x * 8];
  }
}

// Exact softplus for the generic (buckets != 1) path.
__device__ __forceinline__ float softplus_f(float x) {
  float ax = fabsf(x);
  float t = __expf(-ax);
  float corr;
  if (__builtin_expect(ax < 5.0f, 0)) corr = __logf(1.0f + t);
  else                                corr = t - 0.5f * t * t;
  return fmaxf(x, 0.0f) + corr;
}

// C = A(img) x B(prof)^T in fp8 e4m3 via MX MFMA 16x16x128, unit scales (e8m0=127).
//
// r28 = r26 RESTORED (best measured: total 247.7, gemm 172.5, MfmaUtil 34.6,
// WRITE 32 B, VGPR 112) + GRP 8 -> 16 (prologue amortization):
//  - r27 POST-MORTEM: 3-ring + counted vmcnt REGRESSED (gemm 172.5 -> 183.4,
//    MfmaUtil -> 31.3, VALU cycles +7%): r26's 2-buffer step already covers
//    the stage latency in-step; the ring added runtime %3 indexing, an asm
//    "memory" clobber that defeated cross-step scheduling, and tail
//    re-stages. m218's counted-vmcnt lever needs a drain-dominated regime;
//    r26's drain exposure is small. REVERTED to __syncthreads 2-buffer.
//  - GRP 16: with B through LDS, global B traffic is GRP-independent
//    (FETCH ~37 MB either way). Doubling the sweep halves the per-CU
//    block-prologue count (4 -> 2 sequential blocks x ~3-4 us dead time:
//    64 KB A-stage + 2 chunk stages + full drain) and halves A re-staging.
//    Inner loop, LDS (131584), barriers, swizzles: byte-identical to r26.
//
// SESSION LEDGER: register levers all dead (128-arch wall: r12/r14/r16/r17/
// r20/r23/r24 spill; runtime idx -> scratch r15). B-through-LDS = first
// structural win (zero-register latency fix, r26: -20 us). Counted-vmcnt
// ring regressed (r27). setprio +2-3 us (r19). Norm unit-stride +2.5 us
// (r21). L2-residency null (r22).
//
// A LDS swizzle (r5-r10, verified): row r = 32 chunks of 16 B; slot s stores
// global chunk (s&~7)|((s&7)^(r&7)); frag ds_read_b128 = structural-minimum
// 8 addr/bank. B LDS swizzle mirrors it per 16-col group (slot q^(r&7)),
// staged by pre-swizzling the GLOBAL source (both-sides rule, verified r26).
//
// XCD mapping: blockIdx%8 = XCD (m09); each XCD owns a 16-strip bm range.
__global__ __launch_bounds__(512, 2) void siglip_gemm(
    const uint8_t* __restrict__ A, const uint8_t* __restrict__ B,
    const float* __restrict__ scale_p, const float* __restrict__ bias_p,
    const int* __restrict__ buckets_p, float* __restrict__ out, int n) {
  __shared__ __align__(16) uint8_t sA[BM * D];     // 64 KB
  __shared__ __align__(16) uint8_t sB[2][32768];   // 64 KB (2 x kc-chunk)
  __shared__ float red[8];

  int tid = threadIdx.x;
  int lane = tid & 63, wave = tid >> 6;            // 8 waves, 2x4 grid
  int quad = lane >> 4, l16 = lane & 15;

  int nb  = n / BM;                      // 128 strips
  int nbn = n / BN;                      // 64 bn tiles of 256 cols
  int bm, grp;
  if (nb == 128) {                       // n = 16384 fast path
    int xcd  = blockIdx.x & 7;
    int rest = blockIdx.x >> 3;          // 0..63
    bm  = xcd * 16 + (rest & 15);
    grp = rest >> 4;                     // 4 groups of GRP=16 bn-tiles
  } else {
    bm  = blockIdx.x % nb;
    grp = blockIdx.x / nb;
  }
  int gcount = nbn - grp * GRP; if (gcount > GRP) gcount = GRP;

  int rowB = bm * BM;
  float escale = __expf(scale_p[0]);
  float scale  = escale * (1.0f / 256.0f);      // undo x16 quant pre-scale
  float bias   = bias_p[0];
  const float LOG2E = 1.4426950408889634f;
  float sl2 = scale * LOG2E, bl2 = bias * LOG2E;
  int buckets = buckets_p[0];

  int wm = (wave >> 2) * 64, wn = (wave & 3) * 64;   // 2x4 wave grid
  int colB = grp * (GRP * BN);

  // Per-thread B-staging offsets (static-indexed, rule #20):
  // linear LDS offset o = i*8192 + tid*16 decodes as (g = o>>11 col-group,
  // r = (o>>7)&15 row, q = (o>>4)&7 slot); source holds slot q^(r&7).
  int so[4], ldo[4];
#pragma unroll
  for (int i = 0; i < 4; i++) {
    int o = i * 8192 + tid * 16;
    int gg = o >> 11, rr = (o >> 7) & 15, qq = (o >> 4) & 7;
    so[i]  = gg * 8192 + rr * 128 + ((qq ^ (rr & 7)) << 4);
    ldo[i] = o;
  }

  // Stage one 32 KB B kc-chunk (cols [COLS, COLS+256), kc = KCS) into half H.
#define STAGE_B(H, COLS, KCS)                                                  \
  {                                                                            \
    const uint8_t* Bs = B + (size_t)(COLS) * 512 + (size_t)(KCS) * 2048;       \
    _Pragma("unroll")                                                          \
    for (int i = 0; i < 4; i++)                                                \
      gld_lds16(Bs + so[i], &sB[(H)][ldo[i]]);                                 \
  }

  // ---- stage the A strip (xor swizzle) + tile0/kc0 B chunk, ONE barrier ----
  {
    const uint8_t* Ag = A + (size_t)rowB * D;
#pragma unroll
    for (int p = 0; p < 8; p++) {
      int c = p * 512 + tid;             // 4096 chunks of 16 B
      int r = c >> 5, s = c & 31;
      int j = (s & ~7) | ((s & 7) ^ (r & 7));
      gld_lds16(Ag + (size_t)r * D + j * 16, &sA[c * 16]);
    }
  }
  STAGE_B(0, colB, 0)
  __syncthreads();

  f32x4 acc[4][4];
#pragma unroll
  for (int i = 0; i < 4; i++)
#pragma unroll
    for (int j = 0; j < 4; j++) { acc[i][j].x = 0.f; acc[i][j].y = 0.f; acc[i][j].z = 0.f; acc[i][j].w = 0.f; }

  float S1p0 = 0.0f, S1p1 = 0.0f, dsum = 0.0f, local = 0.0f;

  int brow = lane >> 2, bcol = (lane & 3) << 1, be = brow & 7;
  int bgrp0 = (wn >> 4);                 // wave's first 16-col group index

  for (int g = 0; g < gcount; g++) {
    int colNext = (g + 1 < gcount) ? colB + BN : colB;   // clamp on last tile

    // ---- 4 kc-steps: stage next chunk async, compute current from LDS ----
#pragma unroll
    for (int kc = 0; kc < 4; kc++) {
      if (kc < 3) { STAGE_B((kc + 1) & 1, colB, kc + 1) }
      else        { STAGE_B(0, colNext, 0) }

      frag32 af[4];
#pragma unroll
      for (int tm = 0; tm < 4; tm++) {
        int ra = wm + tm * 16 + l16, e = ra & 7;
        const uint8_t* ap = &sA[ra * D + kc * 128];
        af[tm].q[0] = *(const uint4*)(ap + (((2 * quad) ^ e) << 4));
        af[tm].q[1] = *(const uint4*)(ap + (((2 * quad + 1) ^ e) << 4));
      }
      __builtin_amdgcn_s_setprio(1);
#pragma unroll
      for (int tn = 0; tn < 4; tn++) {
        frag32 bf;                       // B fragment from LDS (swizzled)
        const uint8_t* bp = &sB[kc & 1][(bgrp0 + tn) * 2048 + brow * 128];
        bf.q[0] = *(const uint4*)(bp + (((bcol)     ^ be) << 4));
        bf.q[1] = *(const uint4*)(bp + (((bcol + 1) ^ be) << 4));
#pragma unroll
        for (int tm = 0; tm < 4; tm++)
          acc[tm][tn] = __builtin_amdgcn_mfma_scale_f32_16x16x128_f8f6f4(
              af[tm].v, bf.v, acc[tm][tn],
              0, 0,            // cbsz/blgp: fp8 e4m3 both
              0, 127,          // scale A: e8m0 127 -> x1.0
              0, 127);         // scale B: e8m0 127 -> x1.0
      }
      __builtin_amdgcn_s_setprio(0);
      __syncthreads();                   // chunk (kc+1) landed; half kc&1 free
    }

    // ---- register-only epilogue for tile g (stage of next kc0 landed) ----
    if (buckets == 1) {
      // v <= -7.28 always => softplus(v) = e^v (t^2/2 term < 3e-4 total, dropped)
#pragma unroll
      for (int tm = 0; tm < 4; tm++)
#pragma unroll
        for (int tn = 0; tn < 4; tn++)
#pragma unroll
          for (int e = 0; e < 4; e++) {
            float t = fast_exp2(__builtin_fmaf(acc[tm][tn][e], sl2, bl2));
            if (tn & 1) S1p1 += t; else S1p0 += t;
          }
      if (rowB + wm == colB + wn) {      // wave's 64x64 crosses the diagonal
#pragma unroll
        for (int tm = 0; tm < 4; tm++)
#pragma unroll
          for (int e = 0; e < 4; e++)
            if (quad * 4 + e == l16)     // diag: softplus(-v) = softplus(v) - v
              dsum += __builtin_fmaf(acc[tm][tm][e], scale, bias);
      }
    } else {
      unsigned bs = (unsigned)n / (unsigned)buckets;
#pragma unroll
      for (int tm = 0; tm < 4; tm++)
#pragma unroll
        for (int tn = 0; tn < 4; tn++)
#pragma unroll
          for (int e = 0; e < 4; e++) {
            int r = rowB + wm + tm * 16 + quad * 4 + e;
            int c = colB + wn + tn * 16 + l16;
            if ((unsigned)r / bs != (unsigned)c / bs) continue;
            float v = __builtin_fmaf(acc[tm][tn][e], scale, bias);
            local += softplus_f((r == c) ? -v : v);
          }
    }

    // reset accumulators for next tile
#pragma unroll
    for (int i = 0; i < 4; i++)
#pragma unroll
      for (int j = 0; j < 4; j++) { acc[i][j].x = 0.f; acc[i][j].y = 0.f; acc[i][j].z = 0.f; acc[i][j].w = 0.f; }

    colB = colNext;
  }
#undef STAGE_B

  // ---- block reduction, one atomic ----
  float wsum = local + S1p0 + S1p1 - dsum;
#pragma unroll
  for (int m = 1; m < 64; m <<= 1) wsum += __shfl_xor(wsum, m, 64);
  if (lane == 0) red[wave] = wsum;
  __syncthreads();
  if (tid == 0) {
    float bsum = (red[0] + red[1]) + (red[2] + red[3])
               + (red[4] + red[5]) + (red[6] + red[7]);
    atomicAdd(out, bsum * (1.0f / (float)n));
  }
}

extern "C" void kernel_launch(void* const* d_in, const int* in_sizes, int n_in,
                              void* d_out, int out_size, void* d_ws, size_t ws_size,
                              hipStream_t stream) {
  const float* img  = (const float*)d_in[0];
  const float* prof = (const float*)d_in[1];
  const float* lsc  = (const float*)d_in[2];
  const float* bia  = (const float*)d_in[3];
  const int*   bkt  = (const int*)d_in[4];
  float* out = (float*)d_out;

  int n = in_sizes[0] / D;                 // 16384
  uint8_t* wsA = (uint8_t*)d_ws;           // n*512 fp8, row-major
  uint8_t* wsB = wsA + (size_t)n * D;      // n*512 fp8, packed fragment layout

  norm_kernel<<<(2 * n) / 16, 1024, 0, stream>>>(img, prof, wsA, wsB, out, n);
  int nb   = n / BM;                       // 128
  int nbn  = n / BN;                       // 64
  int ngrp = (nbn + GRP - 1) / GRP;        // 4
  siglip_gemm<<<nb * ngrp, 512, 0, stream>>>(wsA, wsB, lsc, bia, bkt, out, n);
}